// Round 2
// baseline (205.347 us; speedup 1.0000x reference)
//
#include <hip/hip_runtime.h>
#include <cmath>

#define NT 144
#define NTERMS 18

// Per-row: a = 1 + p*s in [1,2), sp = s + 1/1.65.
// P(a,x) = n1 * x^a * e^-x / (d1 * Gamma(a+1)), where
//   n1/d1 = 1 + x/(a+1)(1 + x/(a+2)(...(1 + x/(a+N))...))
//   d_k = prod_{m=k..N}(a+m)  -- x-independent, precomputed per row.
// Fixed N=18 terms: worst-case truncation (a=1, x=6.27) gives P error ~1e-5,
// far under the 1.14e-3 output tolerance. One code path -> no divergence.
//
// __builtin_amdgcn_logf  == v_log_f32  (log2)
// __builtin_amdgcn_exp2f == v_exp_f32  (2^x)

__global__ __launch_bounds__(256) void dynangio_kernel(
    const float* __restrict__ x,
    const float* __restrict__ t,
    const float* __restrict__ alpha,
    const float* __restrict__ R,
    float* __restrict__ out,
    int B)
{
    __shared__ float sh_t[NT];
    __shared__ float sh_re[NT];
    const int tid = threadIdx.x;
    if (tid < NT) {
        float al = alpha[tid];
        sh_t[tid]  = t[tid];
        // E = sin(deg2rad(alpha)); fold R*E into one table
        sh_re[tid] = R[tid] * sinf(al * 0.017453292519943295f);
    }
    __syncthreads();

    const int i = blockIdx.x * blockDim.x + tid;
    if (i >= B) return;

    const float4 xi = reinterpret_cast<const float4*>(x)[i];
    const float dt  = xi.x;   // delta_t
    const float s   = xi.y;
    const float p   = xi.z;
    const float amp = xi.w;

    const float T1B   = 1.65f;
    const float TAU   = 1.8f;
    const float LOG2E = 1.4426950408889634f;

    const float u  = p * s;          // a - 1, in [0,1)
    const float a  = 1.0f + u;
    const float sp = s + (1.0f / T1B);

    // Gamma(1+u), u in [0,1): A&S 6.1.36 poly, |err| <= 3e-7
    float g = 0.035868343f;
    g = g * u - 0.193527818f;
    g = g * u + 0.482199394f;
    g = g * u - 0.756704078f;
    g = g * u + 0.918206857f;
    g = g * u - 0.897056937f;
    g = g * u + 0.988205891f;
    g = g * u - 0.577191652f;
    g = g * u + 1.0f;
    const float Ga1 = (1.0f + u) * g;   // Gamma(a+1) = Gamma(2+u) = (1+u)*Gamma(1+u)

    // dk[k] = prod_{m=k..N}(a+m), k = 1..N  (x-independent)
    float dk[NTERMS + 1];
    dk[NTERMS] = a + (float)NTERMS;
    #pragma unroll
    for (int k = NTERMS - 1; k >= 1; --k)
        dk[k] = (a + (float)k) * dk[k + 1];

    const float invDG = 1.0f / (dk[1] * Ga1);

    // SF = 2*exp(-dt/T1B)*(s/sp)^a  (s==0 -> log2=-inf -> SF=0, correct limit)
    const float ls  = __builtin_amdgcn_logf(s);
    const float lsp = __builtin_amdgcn_logf(sp);
    const float SF  = 2.0f * __builtin_amdgcn_exp2f(a * (ls - lsp) - dt * (LOG2E / T1B));

    const float crow  = amp * SF * invDG;
    const float spdt  = sp * dt;
    const float spTau = sp * TAU;

    float* __restrict__ orow = out + (size_t)i * NT;

    #pragma unroll 1
    for (int jb = 0; jb < NT; jb += 4) {
        float4 res;
        #pragma unroll
        for (int q = 0; q < 4; ++q) {
            const int j = jb + q;
            const float x1 = sp * sh_t[j] - spdt;          // > 0.48 always
            const float x2 = fmaxf(x1 - spTau, 0.0f);

            float n1 = 1.0f, n2 = 1.0f;
            #pragma unroll
            for (int k = NTERMS; k >= 1; --k) {
                n1 = __builtin_fmaf(x1, n1, dk[k]);
                n2 = __builtin_fmaf(x2, n2, dk[k]);
            }
            // x^a * e^-x = exp2(a*log2(x) - x*log2(e)); x==0 -> exp2(-inf)=0
            const float e1 = __builtin_amdgcn_exp2f(a * __builtin_amdgcn_logf(x1) - x1 * LOG2E);
            const float e2 = __builtin_amdgcn_exp2f(a * __builtin_amdgcn_logf(x2) - x2 * LOG2E);

            const float gg = n1 * e1 - n2 * e2;            // G * d1 * Gamma(a+1)
            (&res.x)[q] = crow * sh_re[j] * gg;
        }
        *reinterpret_cast<float4*>(orow + jb) = res;
    }
}

extern "C" void kernel_launch(void* const* d_in, const int* in_sizes, int n_in,
                              void* d_out, int out_size, void* d_ws, size_t ws_size,
                              hipStream_t stream) {
    const float* x     = (const float*)d_in[0];
    const float* t     = (const float*)d_in[1];
    const float* alpha = (const float*)d_in[2];
    const float* R     = (const float*)d_in[3];
    float* out = (float*)d_out;

    const int B = in_sizes[0] / 4;
    const int threads = 256;
    const int blocks = (B + threads - 1) / threads;
    hipLaunchKernelGGL(dynangio_kernel, dim3(blocks), dim3(threads), 0, stream,
                       x, t, alpha, R, out, B);
}

// Round 3
// 196.349 us; speedup vs baseline: 1.0458x; 1.0458x over previous
//
#include <hip/hip_runtime.h>
#include <cmath>

#define NT 144

typedef float v2f __attribute__((ext_vector_type(2)));

// Per-row: a = 1 + p*s in [1,2), sp = s + 1/1.65.
// P(a,x) = n * x^a * e^-x / (d1 * Gamma(a+1)), where n is the rational-form
// Horner evaluation of the lower-incomplete-gamma series with x-independent
// denominators d_k = prod_{m=k..18}(a+m), held in NAMED scalars (no local
// arrays -> no scratch). n1 (x=x1) and n2 (x=x2) chains are packed into one
// float2 vector chain -> v_pk_fma_f32 (2 FMAs/lane/instr).
// Fixed 18 terms: worst-case truncation (a=1, x=6.27) error ~1e-5 in P.

__global__ __launch_bounds__(256) void dynangio_kernel(
    const float* __restrict__ x,
    const float* __restrict__ t,
    const float* __restrict__ alpha,
    const float* __restrict__ R,
    float* __restrict__ out,
    int B)
{
    __shared__ alignas(16) float sh_t[NT];
    __shared__ alignas(16) float sh_re[NT];
    const int tid = threadIdx.x;
    if (tid < NT) {
        float al = alpha[tid];
        sh_t[tid]  = t[tid];
        sh_re[tid] = R[tid] * sinf(al * 0.017453292519943295f);  // R * sin(deg2rad(alpha))
    }
    __syncthreads();

    const int i = blockIdx.x * blockDim.x + tid;
    if (i >= B) return;

    const float4 xi = reinterpret_cast<const float4*>(x)[i];
    const float dt  = xi.x;
    const float s   = xi.y;
    const float p   = xi.z;
    const float amp = xi.w;

    const float T1B   = 1.65f;
    const float TAU   = 1.8f;
    const float LOG2E = 1.4426950408889634f;

    const float u  = p * s;            // a-1 in [0,1)
    const float a  = 1.0f + u;
    const float sp = s + (1.0f / T1B);

    // Gamma(1+u), u in [0,1): A&S 6.1.36, |err| <= 3e-7
    float g = 0.035868343f;
    g = g * u - 0.193527818f;
    g = g * u + 0.482199394f;
    g = g * u - 0.756704078f;
    g = g * u + 0.918206857f;
    g = g * u - 0.897056937f;
    g = g * u + 0.988205891f;
    g = g * u - 0.577191652f;
    g = g * u + 1.0f;
    const float Ga1 = (1.0f + u) * g;  // Gamma(a+1)

    // d_k = prod_{m=k..18}(a+m) -- named scalars, stays in VGPRs
    const float d18 = a + 18.0f;
    const float d17 = (a + 17.0f) * d18;
    const float d16 = (a + 16.0f) * d17;
    const float d15 = (a + 15.0f) * d16;
    const float d14 = (a + 14.0f) * d15;
    const float d13 = (a + 13.0f) * d14;
    const float d12 = (a + 12.0f) * d13;
    const float d11 = (a + 11.0f) * d12;
    const float d10 = (a + 10.0f) * d11;
    const float d9  = (a +  9.0f) * d10;
    const float d8  = (a +  8.0f) * d9;
    const float d7  = (a +  7.0f) * d8;
    const float d6  = (a +  6.0f) * d7;
    const float d5  = (a +  5.0f) * d6;
    const float d4  = (a +  4.0f) * d5;
    const float d3  = (a +  3.0f) * d4;
    const float d2  = (a +  2.0f) * d3;
    const float d1  = (a +  1.0f) * d2;

    const float invDG = 1.0f / (d1 * Ga1);

    // SF = 2*exp(-dt/T1B)*(s/sp)^a   (log2-domain; s==0 -> -inf -> 0, correct)
    const float SF = 2.0f * __builtin_amdgcn_exp2f(
        a * (__builtin_amdgcn_logf(s) - __builtin_amdgcn_logf(sp))
        - dt * (LOG2E / T1B));

    const float crow  = amp * SF * invDG;
    const float nspdt = -sp * dt;
    const float spTau = sp * TAU;

    auto elem = [&](float tj, float rej) -> float {
        const float x1 = __builtin_fmaf(sp, tj, nspdt);   // > 0.48 always
        const float x2 = fmaxf(x1 - spTau, 0.0f);
        v2f X; X.x = x1; X.y = x2;
        v2f N = {1.0f, 1.0f};
        // packed Horner: N = X*N + d_k   (v_pk_fma_f32)
        N = X * N + d18;  N = X * N + d17;  N = X * N + d16;
        N = X * N + d15;  N = X * N + d14;  N = X * N + d13;
        N = X * N + d12;  N = X * N + d11;  N = X * N + d10;
        N = X * N + d9;   N = X * N + d8;   N = X * N + d7;
        N = X * N + d6;   N = X * N + d5;   N = X * N + d4;
        N = X * N + d3;   N = X * N + d2;   N = X * N + d1;
        // x^a * e^-x = exp2(a*log2(x) - x*log2e);  x2==0 -> exp2(-inf)=0
        v2f L; L.x = __builtin_amdgcn_logf(x1); L.y = __builtin_amdgcn_logf(x2);
        v2f Ee = a * L - X * LOG2E;                       // packed fma
        const float e1 = __builtin_amdgcn_exp2f(Ee.x);
        const float e2 = __builtin_amdgcn_exp2f(Ee.y);
        const float gg = __builtin_fmaf(N.x, e1, -(N.y * e2));
        return (crow * rej) * gg;
    };

    float* __restrict__ orow = out + (size_t)i * NT;
    const float4* sh_t4  = reinterpret_cast<const float4*>(sh_t);
    const float4* sh_re4 = reinterpret_cast<const float4*>(sh_re);

    #pragma unroll 2
    for (int jb = 0; jb < NT / 4; ++jb) {
        const float4 tj4 = sh_t4[jb];
        const float4 re4 = sh_re4[jb];
        float4 res;
        res.x = elem(tj4.x, re4.x);
        res.y = elem(tj4.y, re4.y);
        res.z = elem(tj4.z, re4.z);
        res.w = elem(tj4.w, re4.w);
        reinterpret_cast<float4*>(orow)[jb] = res;
    }
}

extern "C" void kernel_launch(void* const* d_in, const int* in_sizes, int n_in,
                              void* d_out, int out_size, void* d_ws, size_t ws_size,
                              hipStream_t stream) {
    const float* x     = (const float*)d_in[0];
    const float* t     = (const float*)d_in[1];
    const float* alpha = (const float*)d_in[2];
    const float* R     = (const float*)d_in[3];
    float* out = (float*)d_out;

    const int B = in_sizes[0] / 4;
    const int threads = 256;
    const int blocks = (B + threads - 1) / threads;
    hipLaunchKernelGGL(dynangio_kernel, dim3(blocks), dim3(threads), 0, stream,
                       x, t, alpha, R, out, B);
}